// Round 1
// baseline (298.144 us; speedup 1.0000x reference)
//
#include <hip/hip_runtime.h>
#include <math.h>

// Problem constants (B=2, N=512, C=64, H=8)
constexpr int BDIM    = 256;        // threads per block
constexpr int TILE    = 256;        // n-rows staged per tile (thread t owns n = tile*256 + t)
constexpr int NDIM    = 512;
constexpr int CDIM    = 64;
constexpr int HDIM    = 8;
constexpr int CHALF   = 32;         // c-columns staged per phase (keeps LDS < 64 KiB, 4 blocks/CU)
constexpr int LSTRIDE = CHALF + 1;  // 33: stride ≡ 1 mod 32 -> conflict-free per-row reads

__global__ __launch_bounds__(BDIM)
void mha_kernel(const float* __restrict__ q,
                const float* __restrict__ kk,
                const float* __restrict__ mask,
                const float* __restrict__ W,      // (H, 2C) row-major, wave-uniform -> SGPRs
                const float* __restrict__ bias,   // (H,)
                float* __restrict__ out)          // (B, N, N, H)
{
    __shared__ float tile_lds[TILE * LSTRIDE];    // 33,792 B
    __shared__ float red[4 * HDIM];
    __shared__ float rsum_lds[HDIM];

    const int bm = blockIdx.x;      // b*512 + m
    const int t  = threadIdx.x;

    const float* qrow = q  + (size_t)bm * NDIM * CDIM;
    const float* krow = kk + (size_t)bm * NDIM * CDIM;

    float val[2][HDIM];             // exp'd masked attn for this thread's 2 n's
    float psum[HDIM];
#pragma unroll
    for (int h = 0; h < HDIM; ++h) psum[h] = 0.0f;

#pragma unroll
    for (int tl = 0; tl < 2; ++tl) {
        const int n0 = tl * TILE;
        float acc[HDIM];
#pragma unroll
        for (int h = 0; h < HDIM; ++h) acc[h] = 0.0f;

        // 4 phases: ph0 = q cols 0-31, ph1 = q cols 32-63, ph2 = k cols 0-31, ph3 = k cols 32-63
        // W column offset is simply ph*32 within the 128-wide W row.
        for (int ph = 0; ph < 4; ++ph) {
            const float* srcbase = (ph < 2) ? qrow : krow;
            const float* src = srcbase + (size_t)n0 * CDIM + (ph & 1) * CHALF;

            __syncthreads();        // previous phase done reading tile_lds
            // stage TILE x CHALF floats, coalesced float4 loads
#pragma unroll
            for (int i = 0; i < 8; ++i) {
                int f4 = t + i * BDIM;          // float4 index 0..2047
                int n  = f4 >> 3;               // 8 float4 per staged row
                int c4 = (f4 & 7) << 2;
                float4 v = *(const float4*)(src + n * CDIM + c4);
                float* d = &tile_lds[n * LSTRIDE + c4];
                d[0] = v.x; d[1] = v.y; d[2] = v.z; d[3] = v.w;
            }
            __syncthreads();

            // thread t owns row n = t of this tile
            float x[CHALF];
            const float* xs = &tile_lds[t * LSTRIDE];
#pragma unroll
            for (int c = 0; c < CHALF; ++c) x[c] = xs[c];

            const float* wp = W + ph * CHALF;   // uniform address -> s_load
#pragma unroll
            for (int h = 0; h < HDIM; ++h) {
                float a = acc[h];
#pragma unroll
                for (int c = 0; c < CHALF; ++c)
                    a = fmaf(x[c], wp[h * 2 * CDIM + c], a);
                acc[h] = a;
            }
        }

        const float mval = mask[bm * NDIM + n0 + t];
#pragma unroll
        for (int h = 0; h < HDIM; ++h) {
            float v = __expf(acc[h] + bias[h]) * mval;
            val[tl][h] = v;
            psum[h] += v;
        }
    }

    // block-wide sum over n (axis=2): wave butterfly, then cross-wave via LDS
#pragma unroll
    for (int h = 0; h < HDIM; ++h) {
        float s = psum[h];
#pragma unroll
        for (int off = 32; off >= 1; off >>= 1)
            s += __shfl_xor(s, off, 64);
        psum[h] = s;
    }
    const int lane = t & 63;
    const int wid  = t >> 6;
    if (lane == 0) {
#pragma unroll
        for (int h = 0; h < HDIM; ++h) red[wid * HDIM + h] = psum[h];
    }
    __syncthreads();
    if (t < HDIM) {
        float s = red[t] + red[HDIM + t] + red[2 * HDIM + t] + red[3 * HDIM + t];
        rsum_lds[t] = 1.0f / s;
    }
    __syncthreads();

    float rs[HDIM];
#pragma unroll
    for (int h = 0; h < HDIM; ++h) rs[h] = rsum_lds[h];

    float* orow = out + (size_t)bm * NDIM * HDIM;
#pragma unroll
    for (int tl = 0; tl < 2; ++tl) {
        const int n = tl * TILE + t;
        float4 lo = make_float4(val[tl][0] * rs[0], val[tl][1] * rs[1],
                                val[tl][2] * rs[2], val[tl][3] * rs[3]);
        float4 hi = make_float4(val[tl][4] * rs[4], val[tl][5] * rs[5],
                                val[tl][6] * rs[6], val[tl][7] * rs[7]);
        float4* op = (float4*)(orow + (size_t)n * HDIM);
        op[0] = lo;
        op[1] = hi;
    }
}

extern "C" void kernel_launch(void* const* d_in, const int* in_sizes, int n_in,
                              void* d_out, int out_size, void* d_ws, size_t ws_size,
                              hipStream_t stream) {
    const float* q    = (const float*)d_in[0];
    const float* k    = (const float*)d_in[1];
    const float* mask = (const float*)d_in[2];
    const float* W    = (const float*)d_in[3];
    const float* b    = (const float*)d_in[4];
    float* out = (float*)d_out;

    hipLaunchKernelGGL(mha_kernel, dim3(2 * NDIM), dim3(BDIM), 0, stream,
                       q, k, mask, W, b, out);
}

// Round 2
// 296.615 us; speedup vs baseline: 1.0052x; 1.0052x over previous
//
#include <hip/hip_runtime.h>
#include <math.h>

// Problem constants (B=2, N=512, C=64, H=8)
constexpr int BDIM = 256;
constexpr int NDIM = 512;
constexpr int CDIM = 64;
constexpr int HDIM = 8;

// One block per (b,m). Thread t owns rows n = t and n = t+256.
// Each thread loads its own contiguous 256 B q-row / k-row directly to
// registers (16 independent dwordx4 in flight, no LDS staging, no barriers
// until the final 8-value block reduction). W/bias are wave-uniform ->
// scalar loads, FMA takes the SGPR operand directly.
__global__ __launch_bounds__(BDIM, 4)
void mha_kernel(const float* __restrict__ q,
                const float* __restrict__ kk,
                const float* __restrict__ mask,
                const float* __restrict__ W,      // (H, 2C) row-major
                const float* __restrict__ bias,   // (H,)
                float* __restrict__ out)          // (B, N, N, H)
{
    __shared__ float red[4 * HDIM];
    __shared__ float rsum_lds[HDIM];

    const int bm = blockIdx.x;      // b*512 + m
    const int t  = threadIdx.x;

    const float* qrow = q  + (size_t)bm * NDIM * CDIM;
    const float* krow = kk + (size_t)bm * NDIM * CDIM;

    float val[2][HDIM];
    float psum[HDIM];
#pragma unroll
    for (int h = 0; h < HDIM; ++h) psum[h] = 0.0f;

#pragma unroll
    for (int tl = 0; tl < 2; ++tl) {
        const int n = tl * BDIM + t;

        float acc[HDIM];
#pragma unroll
        for (int h = 0; h < HDIM; ++h) acc[h] = 0.0f;

        // ---- q row: 16 independent float4 loads -> x[64] ----
        {
            const float4* qp = (const float4*)(qrow + (size_t)n * CDIM);
            float x[CDIM];
#pragma unroll
            for (int j = 0; j < 16; ++j) {
                float4 v = qp[j];
                x[4 * j + 0] = v.x; x[4 * j + 1] = v.y;
                x[4 * j + 2] = v.z; x[4 * j + 3] = v.w;
            }
#pragma unroll
            for (int h = 0; h < HDIM; ++h) {
                const float* wq = W + h * 2 * CDIM;      // uniform -> s_load
                float a = acc[h];
#pragma unroll
                for (int c = 0; c < CDIM; ++c)
                    a = fmaf(x[c], wq[c], a);
                acc[h] = a;
            }
        }

        // ---- k row: reuse x[] registers ----
        {
            const float4* kp = (const float4*)(krow + (size_t)n * CDIM);
            float x[CDIM];
#pragma unroll
            for (int j = 0; j < 16; ++j) {
                float4 v = kp[j];
                x[4 * j + 0] = v.x; x[4 * j + 1] = v.y;
                x[4 * j + 2] = v.z; x[4 * j + 3] = v.w;
            }
#pragma unroll
            for (int h = 0; h < HDIM; ++h) {
                const float* wk = W + h * 2 * CDIM + CDIM;
                float a = acc[h];
#pragma unroll
                for (int c = 0; c < CDIM; ++c)
                    a = fmaf(x[c], wk[c], a);
                acc[h] = a;
            }
        }

        const float mval = mask[bm * NDIM + n];
#pragma unroll
        for (int h = 0; h < HDIM; ++h) {
            float v = __expf(acc[h] + bias[h]) * mval;
            val[tl][h] = v;
            psum[h] += v;
        }
    }

    // block-wide sum over n (axis=2): wave butterfly, then cross-wave via LDS
#pragma unroll
    for (int h = 0; h < HDIM; ++h) {
        float s = psum[h];
#pragma unroll
        for (int off = 32; off >= 1; off >>= 1)
            s += __shfl_xor(s, off, 64);
        psum[h] = s;
    }
    const int lane = t & 63;
    const int wid  = t >> 6;
    if (lane == 0) {
#pragma unroll
        for (int h = 0; h < HDIM; ++h) red[wid * HDIM + h] = psum[h];
    }
    __syncthreads();
    if (t < HDIM) {
        float s = red[t] + red[HDIM + t] + red[2 * HDIM + t] + red[3 * HDIM + t];
        rsum_lds[t] = 1.0f / s;
    }
    __syncthreads();

    float rs[HDIM];
#pragma unroll
    for (int h = 0; h < HDIM; ++h) rs[h] = rsum_lds[h];

    float* orow = out + (size_t)bm * NDIM * HDIM;
#pragma unroll
    for (int tl = 0; tl < 2; ++tl) {
        const int n = tl * BDIM + t;
        float4 lo = make_float4(val[tl][0] * rs[0], val[tl][1] * rs[1],
                                val[tl][2] * rs[2], val[tl][3] * rs[3]);
        float4 hi = make_float4(val[tl][4] * rs[4], val[tl][5] * rs[5],
                                val[tl][6] * rs[6], val[tl][7] * rs[7]);
        float4* op = (float4*)(orow + (size_t)n * HDIM);
        op[0] = lo;
        op[1] = hi;
    }
}

extern "C" void kernel_launch(void* const* d_in, const int* in_sizes, int n_in,
                              void* d_out, int out_size, void* d_ws, size_t ws_size,
                              hipStream_t stream) {
    const float* q    = (const float*)d_in[0];
    const float* k    = (const float*)d_in[1];
    const float* mask = (const float*)d_in[2];
    const float* W    = (const float*)d_in[3];
    const float* b    = (const float*)d_in[4];
    float* out = (float*)d_out;

    hipLaunchKernelGGL(mha_kernel, dim3(2 * NDIM), dim3(BDIM), 0, stream,
                       q, k, mask, W, b, out);
}

// Round 3
// 294.193 us; speedup vs baseline: 1.0134x; 1.0082x over previous
//
#include <hip/hip_runtime.h>
#include <math.h>

// Problem constants (B=2, N=512, C=64, H=8)
constexpr int BDIM = 512;   // 8 waves; with 4 blocks/CU -> 32 waves/CU (100% occupancy)
constexpr int NDIM = 512;
constexpr int CDIM = 64;
constexpr int HDIM = 8;
constexpr int NWAVE = BDIM / 64;

// One block per (b,m); thread t owns row n = t. Each thread loads its own
// contiguous 256 B q-row / k-row directly to registers. W/bias are
// wave-uniform -> scalar loads; FMA takes the SGPR operand directly.
// __launch_bounds__(512, 8): 8 waves/EU min -> VGPR cap 64 (R2 measured 48
// with 2x the per-thread state, so no spill risk) -> full 32 waves/CU.
__global__ __launch_bounds__(BDIM, 8)
void mha_kernel(const float* __restrict__ q,
                const float* __restrict__ kk,
                const float* __restrict__ mask,
                const float* __restrict__ W,      // (H, 2C) row-major
                const float* __restrict__ bias,   // (H,)
                float* __restrict__ out)          // (B, N, N, H)
{
    __shared__ float red[NWAVE * HDIM];
    __shared__ float rsum_lds[HDIM];

    const int bm = blockIdx.x;      // b*512 + m
    const int t  = threadIdx.x;
    const int n  = t;

    const float* qrow = q  + (size_t)bm * NDIM * CDIM;
    const float* krow = kk + (size_t)bm * NDIM * CDIM;

    float acc[HDIM];
#pragma unroll
    for (int h = 0; h < HDIM; ++h) acc[h] = 0.0f;

    // ---- q row ----
    {
        const float4* qp = (const float4*)(qrow + (size_t)n * CDIM);
        float x[CDIM];
#pragma unroll
        for (int j = 0; j < 16; ++j) {
            float4 v = qp[j];
            x[4 * j + 0] = v.x; x[4 * j + 1] = v.y;
            x[4 * j + 2] = v.z; x[4 * j + 3] = v.w;
        }
#pragma unroll
        for (int h = 0; h < HDIM; ++h) {
            const float* wq = W + h * 2 * CDIM;      // uniform -> s_load
            float a = acc[h];
#pragma unroll
            for (int c = 0; c < CDIM; ++c)
                a = fmaf(x[c], wq[c], a);
            acc[h] = a;
        }
    }

    // ---- k row ----
    {
        const float4* kp = (const float4*)(krow + (size_t)n * CDIM);
        float x[CDIM];
#pragma unroll
        for (int j = 0; j < 16; ++j) {
            float4 v = kp[j];
            x[4 * j + 0] = v.x; x[4 * j + 1] = v.y;
            x[4 * j + 2] = v.z; x[4 * j + 3] = v.w;
        }
#pragma unroll
        for (int h = 0; h < HDIM; ++h) {
            const float* wk = W + h * 2 * CDIM + CDIM;
            float a = acc[h];
#pragma unroll
            for (int c = 0; c < CDIM; ++c)
                a = fmaf(x[c], wk[c], a);
            acc[h] = a;
        }
    }

    const float mval = mask[bm * NDIM + n];
    float val[HDIM];
    float psum[HDIM];
#pragma unroll
    for (int h = 0; h < HDIM; ++h) {
        float v = __expf(acc[h] + bias[h]) * mval;
        val[h]  = v;
        psum[h] = v;
    }

    // block-wide sum over n (axis=2): wave butterfly, then cross-wave via LDS
#pragma unroll
    for (int h = 0; h < HDIM; ++h) {
        float s = psum[h];
#pragma unroll
        for (int off = 32; off >= 1; off >>= 1)
            s += __shfl_xor(s, off, 64);
        psum[h] = s;
    }
    const int lane = t & 63;
    const int wid  = t >> 6;
    if (lane == 0) {
#pragma unroll
        for (int h = 0; h < HDIM; ++h) red[wid * HDIM + h] = psum[h];
    }
    __syncthreads();
    if (t < HDIM) {
        float s = 0.0f;
#pragma unroll
        for (int w = 0; w < NWAVE; ++w) s += red[w * HDIM + t];
        rsum_lds[t] = 1.0f / s;
    }
    __syncthreads();

    float rs[HDIM];
#pragma unroll
    for (int h = 0; h < HDIM; ++h) rs[h] = rsum_lds[h];

    float* orow = out + (size_t)bm * NDIM * HDIM;
    float4 lo = make_float4(val[0] * rs[0], val[1] * rs[1],
                            val[2] * rs[2], val[3] * rs[3]);
    float4 hi = make_float4(val[4] * rs[4], val[5] * rs[5],
                            val[6] * rs[6], val[7] * rs[7]);
    float4* op = (float4*)(orow + (size_t)n * HDIM);
    op[0] = lo;
    op[1] = hi;
}

extern "C" void kernel_launch(void* const* d_in, const int* in_sizes, int n_in,
                              void* d_out, int out_size, void* d_ws, size_t ws_size,
                              hipStream_t stream) {
    const float* q    = (const float*)d_in[0];
    const float* k    = (const float*)d_in[1];
    const float* mask = (const float*)d_in[2];
    const float* W    = (const float*)d_in[3];
    const float* b    = (const float*)d_in[4];
    float* out = (float*)d_out;

    hipLaunchKernelGGL(mha_kernel, dim3(2 * NDIM), dim3(BDIM), 0, stream,
                       q, k, mask, W, b, out);
}